// Round 8
// baseline (240.198 us; speedup 1.0000x reference)
//
#include <hip/hip_runtime.h>
#include <hip/hip_bf16.h>

#define NB 4096
#define NT 50
#define NH 128
#define NINT 4
#define ROWS 32  // batch rows per block

typedef float f32x4 __attribute__((ext_vector_type(4)));
typedef __bf16 bf16x8 __attribute__((ext_vector_type(8)));
typedef short short8 __attribute__((ext_vector_type(8)));

#define L2E 1.4426950408889634f

__device__ __forceinline__ float frcp(float x) { return __builtin_amdgcn_rcpf(x); }

// exp2(-x) in one instruction: v_exp_f32 computes 2^x; neg is a free src modifier.
__device__ __forceinline__ float exp2neg(float x) {
  float r;
  asm("v_exp_f32 %0, -%1" : "=v"(r) : "v"(x));
  return r;
}

__device__ __forceinline__ unsigned short bfbits(float f) {
  __bf16 b = (__bf16)f;  // native RTNE; pairs pack to v_cvt_pk_bf16_f32
  return __builtin_bit_cast(unsigned short, b);
}

// Grid: 512 blocks = NINT(4) * (NB/32).  Block: 512 threads = 8 waves.
// R8 lever: R7 was LDS-capped at 1 block/CU (91KB > 80KB), pinning occupancy
// at 2 waves/SIMD while VGPR=124 allowed 4.  ROWS 64->32 cuts LDS to 45.5KB
// -> 2 independent blocks/CU (4 waves/SIMD); the blocks share no barriers, so
// one block's barrier/waitcnt drain overlaps the other's MFMA+VALU (m114).
// REGISTER BUDGET remains the second constraint: 96-reg weight set needs the
// (512,2) bound (256-reg budget).  Explicit min-waves=4 bounds caused 64/64
// arch/acc splits and scratch spill (R3-R5: WRITE_SIZE 250-750MB, VGPR=64).
// Here pressure ~110 (hm 8, staging 8) so HW gives 4 waves/SIMD anyway.
__global__ __launch_bounds__(512, 2)
void gru_fused(const int* __restrict__ inputs, const float* __restrict__ emb,
               const float* __restrict__ w_int, const float* __restrict__ w_ih,
               const float* __restrict__ w_hh, const float* __restrict__ b_ih,
               const float* __restrict__ b_hh, const float* __restrict__ h0,
               float* __restrict__ out) {
  __shared__ unsigned short xs[2][ROWS * NH];      // 16 KB x tile, bf16, swizzled
  __shared__ unsigned short hs[2][ROWS * NH];      // 16 KB h tile, bf16, swizzled
  __shared__ __align__(16) float gall[NT * ROWS];  // 6.4 KB pre-thresholded gates
  __shared__ int idxs[NT * ROWS];                  // 6.4 KB token ids

  const int tid = threadIdx.x;
  const int bx = blockIdx.x;
  const int I = bx >> 7;             // interest 0..3
  const int R0 = (bx & 127) * ROWS;  // first batch row
  const int w = tid >> 6;            // wave 0..7
  const int lane = tid & 63;
  const int l15 = lane & 15;
  const int l4 = lane >> 4;
  const int col = w * 16 + l15;      // this lane's output column (0..127)

  // staging/gather mapping: 16 threads per row, 8 floats (32B) each
  const int sr = tid >> 4;   // row 0..31
  const int sp = tid & 15;   // segment

  // ---- token indices ----
  for (int e = tid; e < NT * ROWS; e += 512) {
    int t = e >> 5, r = e & (ROWS - 1);
    idxs[e] = inputs[(size_t)(R0 + r) * NT + t];
  }
  __syncthreads();

  // ---- gate prologue: g[t][r] for ALL timesteps (coalesced, 16 thr/row),
  //      stored PRE-THRESHOLDED: (g>0.01 ? g : 0) ----
  {
    float4 wA[NINT], wB[NINT];
    #pragma unroll
    for (int i = 0; i < NINT; ++i) {
      const float4* p = (const float4*)(w_int + i * NH + sp * 8);
      wA[i] = p[0];
      wB[i] = p[1];
    }
    for (int t = 0; t < NT; ++t) {
      int e = t * ROWS + sr;
      const float4* xr = (const float4*)(emb + (size_t)idxs[e] * NH + sp * 8);
      float4 a = xr[0], b = xr[1];
      float d[NINT];
      #pragma unroll
      for (int i = 0; i < NINT; ++i) {
        d[i] = a.x * wA[i].x + a.y * wA[i].y + a.z * wA[i].z + a.w * wA[i].w +
               b.x * wB[i].x + b.y * wB[i].y + b.z * wB[i].z + b.w * wB[i].w;
      }
      #pragma unroll
      for (int off = 1; off < 16; off <<= 1) {
        #pragma unroll
        for (int i = 0; i < NINT; ++i) d[i] += __shfl_xor(d[i], off, 64);
      }
      if (sp == 0) {
        float sa = d[0] * 10.f, sb = d[1] * 10.f, sc = d[2] * 10.f, sd = d[3] * 10.f;
        float mx = fmaxf(fmaxf(sa, sb), fmaxf(sc, sd));
        float ea = __expf(sa - mx), eb = __expf(sb - mx), ec = __expf(sc - mx),
              ed = __expf(sd - mx);
        float sel = (I == 0) ? ea : (I == 1) ? eb : (I == 2) ? ec : ed;
        float gv = sel * frcp(ea + eb + ec + ed);
        gall[e] = (gv > 0.01f) ? gv : 0.0f;
      }
    }
  }

  // ---- persistent weight fragments in registers (96 VGPR) + biases,
  //      PRE-SCALED so the MFMA result is the exp2 argument:
  //      gates r,i: *log2e   gate n: *2*log2e ----
  // B-operand of 16x16x32: lane holds col=(lane&15), k = (lane>>4)*8 + 0..7
  bf16x8 wih[3][4], whh[3][4];
  float biasRI[2];  // (b_ih+b_hh)*log2e for gates r,i (fused accumulator init)
  float biasNI, biasNH;
  {
    const float gs[3] = {L2E, L2E, 2.0f * L2E};
    #pragma unroll
    for (int g = 0; g < 3; ++g) {
      int oc = g * NH + col;
      #pragma unroll
      for (int kk = 0; kk < 4; ++kk) {
        int k0 = kk * 32 + l4 * 8;
        const float* pi = w_ih + ((size_t)(I * 384 + oc) * NH + k0);
        const float* ph = w_hh + ((size_t)(I * 384 + oc) * NH + k0);
        bf16x8 si, sh;
        #pragma unroll
        for (int e = 0; e < 8; ++e) {
          si[e] = (__bf16)(pi[e] * gs[g]);
          sh[e] = (__bf16)(ph[e] * gs[g]);
        }
        wih[g][kk] = si;
        whh[g][kk] = sh;
      }
    }
    biasRI[0] = (b_ih[I * 384 + col] + b_hh[I * 384 + col]) * L2E;
    biasRI[1] = (b_ih[I * 384 + NH + col] + b_hh[I * 384 + NH + col]) * L2E;
    biasNI = b_ih[I * 384 + 2 * NH + col] * (2.0f * L2E);
    biasNH = b_hh[I * 384 + 2 * NH + col] * (2.0f * L2E);
  }

  // ---- h0 master (fp32 regs) + initial bf16 LDS copy ----
  // C/D layout: col = lane&15, row = (lane>>4)*4 + reg
  float hm[2][4];
  #pragma unroll
  for (int m = 0; m < 2; ++m) {
    #pragma unroll
    for (int j = 0; j < 4; ++j) {
      int row = m * 16 + l4 * 4 + j;
      float v = h0[((size_t)I * NB + R0 + row) * NH + col];
      hm[m][j] = v;
      hs[0][(row * NH + col) ^ ((row & 7) << 3)] = bfbits(v);
    }
  }

  // ---- stage x(0) ----
  {
    const float4* src = (const float4*)(emb + (size_t)idxs[sr] * NH + sp * 8);
    float4 v0 = src[0], v1 = src[1];
    short8 s0;
    s0[0] = bfbits(v0.x); s0[1] = bfbits(v0.y); s0[2] = bfbits(v0.z); s0[3] = bfbits(v0.w);
    s0[4] = bfbits(v1.x); s0[5] = bfbits(v1.y); s0[6] = bfbits(v1.z); s0[7] = bfbits(v1.w);
    int base = sr * NH + sp * 8;
    *(short8*)&xs[0][base ^ ((sr & 7) << 3)] = s0;
  }
  __syncthreads();

  // ---- main recurrence ----
  for (int t = 0; t < NT; ++t) {
    const int cur = t & 1, nxt = cur ^ 1;
    const bool pf = (t + 1 < NT);

    // prefetch x(t+1) into regs; latency hides under the 48 MFMAs
    float4 v0, v1;
    if (pf) {
      const float4* src =
          (const float4*)(emb + (size_t)idxs[(t + 1) * ROWS + sr] * NH + sp * 8);
      v0 = src[0];
      v1 = src[1];
    }

    const unsigned short* hsc = hs[cur];
    const unsigned short* xsc = xs[cur];
    unsigned short* hsn = hs[nxt];

    #pragma unroll
    for (int m = 0; m < 2; ++m) {
      // fused accumulators: aR/aI hold gi+gh (+both biases); aNI/aNH separate
      f32x4 aR = f32x4{biasRI[0], biasRI[0], biasRI[0], biasRI[0]};
      f32x4 aI = f32x4{biasRI[1], biasRI[1], biasRI[1], biasRI[1]};
      f32x4 aNI = f32x4{biasNI, biasNI, biasNI, biasNI};
      f32x4 aNH = f32x4{biasNH, biasNH, biasNH, biasNH};

      int arow = m * 16 + l15;
      int alin = arow * NH + l4 * 8;  // bits 3-4
      int sw2 = (arow & 7) << 3;      // bits 3-5
      __builtin_amdgcn_s_setprio(1);
      #pragma unroll
      for (int kk = 0; kk < 4; ++kk) {
        int e = (alin + kk * 32) ^ sw2;  // kk*32: bits 5-6, carry-free; XOR full index
        bf16x8 ah = __builtin_bit_cast(bf16x8, *(const short8*)&hsc[e]);
        bf16x8 ax = __builtin_bit_cast(bf16x8, *(const short8*)&xsc[e]);
        aR = __builtin_amdgcn_mfma_f32_16x16x32_bf16(ax, wih[0][kk], aR, 0, 0, 0);
        aR = __builtin_amdgcn_mfma_f32_16x16x32_bf16(ah, whh[0][kk], aR, 0, 0, 0);
        aI = __builtin_amdgcn_mfma_f32_16x16x32_bf16(ax, wih[1][kk], aI, 0, 0, 0);
        aI = __builtin_amdgcn_mfma_f32_16x16x32_bf16(ah, whh[1][kk], aI, 0, 0, 0);
        aNI = __builtin_amdgcn_mfma_f32_16x16x32_bf16(ax, wih[2][kk], aNI, 0, 0, 0);
        aNH = __builtin_amdgcn_mfma_f32_16x16x32_bf16(ah, whh[2][kk], aNH, 0, 0, 0);
      }
      __builtin_amdgcn_s_setprio(0);

      const f32x4 gq = *(const f32x4*)&gall[t * ROWS + m * 16 + l4 * 4];
      #pragma unroll
      for (int j = 0; j < 4; ++j) {
        int row = m * 16 + l4 * 4 + j;
        float rg = frcp(1.0f + exp2neg(aR[j]));           // sigm, pre-scaled arg
        float ig = frcp(1.0f + exp2neg(aI[j]));
        float an = fmaf(rg, aNH[j], aNI[j]);              // 2*log2e*(i_n + r*h_n)
        float ng = fmaf(2.0f, frcp(1.0f + exp2neg(an)), -1.0f);  // tanh
        float c = gq[j] * ig;                             // gall pre-thresholded
        float hy = fmaf(c, ng - hm[m][j], hm[m][j]);
        hm[m][j] = hy;
        hsn[(row * NH + col) ^ ((row & 7) << 3)] = bfbits(hy);
      }
    }

    if (pf) {
      short8 s0;
      s0[0] = bfbits(v0.x); s0[1] = bfbits(v0.y); s0[2] = bfbits(v0.z); s0[3] = bfbits(v0.w);
      s0[4] = bfbits(v1.x); s0[5] = bfbits(v1.y); s0[6] = bfbits(v1.z); s0[7] = bfbits(v1.w);
      int base = sr * NH + sp * 8;
      *(short8*)&xs[nxt][base ^ ((sr & 7) << 3)] = s0;
    }
    __syncthreads();
  }

  // ---- epilogue: out[b][I][h] ----
  #pragma unroll
  for (int m = 0; m < 2; ++m) {
    #pragma unroll
    for (int j = 0; j < 4; ++j) {
      int row = m * 16 + l4 * 4 + j;
      out[(size_t)(R0 + row) * (NINT * NH) + I * NH + col] = hm[m][j];
    }
  }
}

extern "C" void kernel_launch(void* const* d_in, const int* in_sizes, int n_in,
                              void* d_out, int out_size, void* d_ws, size_t ws_size,
                              hipStream_t stream) {
  const int* inputs = (const int*)d_in[0];
  const float* emb = (const float*)d_in[1];
  const float* w_int = (const float*)d_in[2];
  const float* w_ih = (const float*)d_in[3];
  const float* w_hh = (const float*)d_in[4];
  const float* b_ih = (const float*)d_in[5];
  const float* b_hh = (const float*)d_in[6];
  const float* h0 = (const float*)d_in[7];
  float* out = (float*)d_out;

  dim3 grid(NINT * (NB / ROWS));  // 512 blocks -> 2 independent blocks/CU
  dim3 block(512);
  gru_fused<<<grid, block, 0, stream>>>(inputs, emb, w_int, w_ih, w_hh, b_ih,
                                        b_hh, h0, out);
}

// Round 10
// 195.696 us; speedup vs baseline: 1.2274x; 1.2274x over previous
//
#include <hip/hip_runtime.h>
#include <hip/hip_bf16.h>

#define NB 4096
#define NT 50
#define NH 128
#define NINT 4
#define ROWS 64  // batch rows per block

typedef float f32x4 __attribute__((ext_vector_type(4)));
typedef __bf16 bf16x8 __attribute__((ext_vector_type(8)));
typedef short short8 __attribute__((ext_vector_type(8)));

#define L2E 1.4426950408889634f

__device__ __forceinline__ float frcp(float x) { return __builtin_amdgcn_rcpf(x); }

// exp2(-x) in one instruction: v_exp_f32 computes 2^x; neg is a free src modifier.
__device__ __forceinline__ float exp2neg(float x) {
  float r;
  asm("v_exp_f32 %0, -%1" : "=v"(r) : "v"(x));
  return r;
}

__device__ __forceinline__ unsigned short bfbits(float f) {
  __bf16 b = (__bf16)f;  // native RTNE; pairs pack to v_cvt_pk_bf16_f32
  return __builtin_bit_cast(unsigned short, b);
}

// Grid: 256 blocks = NINT(4) * (NB/64).  Block: 512 threads = 8 waves, 1/CU.
// OCCUPANCY MODEL (R3-R8): reported VGPR_Count is the arch half; unified
// budget = arch + AGPR.  The 96-reg weight-resident design totals ~190-220
// -> 2 waves/SIMD; an 8-wave block can never double-occupy (needs <=128
// total: infeasible with 96 resident weight regs).  Col-splitting across
// blocks impossible (gh consumes all 128 h-cols each step).  So 2 waves/SIMD
// is structural; optimize within.  (512,2) = 256-reg budget: never spilled.
// R9 LESSON: inline-asm v_mfma is invisible to LLVM's hazard recognizer (not
// isMAI) -> required MFMA->VALU wait-state s_nops are NOT inserted -> NaN.
// Use the builtin; it gets hazards + scheduling for free.
__global__ __launch_bounds__(512, 2)
void gru_fused(const int* __restrict__ inputs, const float* __restrict__ emb,
               const float* __restrict__ w_int, const float* __restrict__ w_ih,
               const float* __restrict__ w_hh, const float* __restrict__ b_ih,
               const float* __restrict__ b_hh, const float* __restrict__ h0,
               float* __restrict__ out) {
  __shared__ unsigned short xs[2][ROWS * NH];  // 32 KB x tile, bf16, swizzled
  __shared__ unsigned short hs[2][ROWS * NH];  // 32 KB h tile, bf16, swizzled
  __shared__ float gbuf[2][ROWS];              // 512 B double-buffered gates
  __shared__ float wintl[NINT * NH];           // 2 KB w_interest
  __shared__ int idxs[NT * ROWS];              // 12.8 KB token ids

  const int tid = threadIdx.x;
  const int bx = blockIdx.x;
  const int I = bx >> 6;          // interest 0..3
  const int R0 = (bx & 63) * ROWS;
  const int w = tid >> 6;         // wave 0..7
  const int lane = tid & 63;
  const int l15 = lane & 15;
  const int l4 = lane >> 4;
  const int col = w * 16 + l15;   // this lane's output column (0..127)

  // staging/gather mapping: 8 threads per row, 16 floats (64B) each
  const int sr = tid >> 3;  // row 0..63
  const int sp = tid & 7;   // segment

  // ---- token indices + w_interest ----
  for (int e = tid; e < NT * ROWS; e += 512) {
    int t = e >> 6, r = e & (ROWS - 1);
    idxs[e] = inputs[(size_t)(R0 + r) * NT + t];
  }
  wintl[tid] = w_int[tid];  // 512 == NINT*NH
  __syncthreads();

  // gate-from-staged-x: dots vs w_int (LDS), 3-level shuffle over the 8-lane
  // row group, softmax+threshold at sp==0 -> gbuf[buf][sr].  Runs in the
  // staging shadow of the main loop (replaces the former 50-iter serial
  // prologue, whose cost R8 exposed by doubling it).
  auto gate_from = [&](int buf, float4 a, float4 b, float4 c, float4 e) {
    float d[NINT];
    #pragma unroll
    for (int i = 0; i < NINT; ++i) {
      const float4* wq = (const float4*)&wintl[i * NH + sp * 16];
      float4 w0 = wq[0], w1 = wq[1], w2 = wq[2], w3 = wq[3];
      d[i] = a.x * w0.x + a.y * w0.y + a.z * w0.z + a.w * w0.w +
             b.x * w1.x + b.y * w1.y + b.z * w1.z + b.w * w1.w +
             c.x * w2.x + c.y * w2.y + c.z * w2.z + c.w * w2.w +
             e.x * w3.x + e.y * w3.y + e.z * w3.z + e.w * w3.w;
    }
    #pragma unroll
    for (int off = 1; off < 8; off <<= 1) {
      #pragma unroll
      for (int i = 0; i < NINT; ++i) d[i] += __shfl_xor(d[i], off, 64);
    }
    if (sp == 0) {
      float sa = d[0] * 10.f, sb = d[1] * 10.f, sc = d[2] * 10.f, sd = d[3] * 10.f;
      float mx = fmaxf(fmaxf(sa, sb), fmaxf(sc, sd));
      float ea = __expf(sa - mx), eb = __expf(sb - mx), ec = __expf(sc - mx),
            ed = __expf(sd - mx);
      float sel = (I == 0) ? ea : (I == 1) ? eb : (I == 2) ? ec : ed;
      float gv = sel * frcp(ea + eb + ec + ed);
      gbuf[buf][sr] = (gv > 0.01f) ? gv : 0.0f;
    }
  };

  // ---- persistent weight fragments in registers (96 VGPR) + biases,
  //      PRE-SCALED so the MFMA result is the exp2 argument:
  //      gates r,i: *log2e   gate n: *2*log2e ----
  // B-operand of 16x16x32: lane holds col=(lane&15), k = (lane>>4)*8 + 0..7
  bf16x8 wih[3][4], whh[3][4];
  float biasRI[2];  // (b_ih+b_hh)*log2e for gates r,i (fused accumulator init)
  float biasNI, biasNH;
  {
    const float gs[3] = {L2E, L2E, 2.0f * L2E};
    #pragma unroll
    for (int g = 0; g < 3; ++g) {
      int oc = g * NH + col;
      #pragma unroll
      for (int kk = 0; kk < 4; ++kk) {
        int k0 = kk * 32 + l4 * 8;
        const float* pi = w_ih + ((size_t)(I * 384 + oc) * NH + k0);
        const float* ph = w_hh + ((size_t)(I * 384 + oc) * NH + k0);
        bf16x8 si, sh;
        #pragma unroll
        for (int e = 0; e < 8; ++e) {
          si[e] = (__bf16)(pi[e] * gs[g]);
          sh[e] = (__bf16)(ph[e] * gs[g]);
        }
        wih[g][kk] = si;
        whh[g][kk] = sh;
      }
    }
    biasRI[0] = (b_ih[I * 384 + col] + b_hh[I * 384 + col]) * L2E;
    biasRI[1] = (b_ih[I * 384 + NH + col] + b_hh[I * 384 + NH + col]) * L2E;
    biasNI = b_ih[I * 384 + 2 * NH + col] * (2.0f * L2E);
    biasNH = b_hh[I * 384 + 2 * NH + col] * (2.0f * L2E);
  }

  // ---- h0 master (fp32 regs) + initial bf16 LDS copy ----
  // C/D layout: col = lane&15, row = (lane>>4)*4 + reg
  float hm[4][4];
  #pragma unroll
  for (int m = 0; m < 4; ++m) {
    #pragma unroll
    for (int j = 0; j < 4; ++j) {
      int row = m * 16 + l4 * 4 + j;
      float v = h0[((size_t)I * NB + R0 + row) * NH + col];
      hm[m][j] = v;
      hs[0][(row * NH + col) ^ ((row & 7) << 3)] = bfbits(v);
    }
  }

  // ---- stage x(0) + gate g(0) ----
  {
    const float4* src = (const float4*)(emb + (size_t)idxs[sr] * NH + sp * 16);
    float4 v0 = src[0], v1 = src[1], v2 = src[2], v3 = src[3];
    short8 s0, s1;
    s0[0] = bfbits(v0.x); s0[1] = bfbits(v0.y); s0[2] = bfbits(v0.z); s0[3] = bfbits(v0.w);
    s0[4] = bfbits(v1.x); s0[5] = bfbits(v1.y); s0[6] = bfbits(v1.z); s0[7] = bfbits(v1.w);
    s1[0] = bfbits(v2.x); s1[1] = bfbits(v2.y); s1[2] = bfbits(v2.z); s1[3] = bfbits(v2.w);
    s1[4] = bfbits(v3.x); s1[5] = bfbits(v3.y); s1[6] = bfbits(v3.z); s1[7] = bfbits(v3.w);
    int base = sr * NH + sp * 16;
    int sw = (sr & 7) << 3;
    *(short8*)&xs[0][base ^ sw] = s0;
    *(short8*)&xs[0][(base + 8) ^ sw] = s1;
    gate_from(0, v0, v1, v2, v3);
  }
  __syncthreads();

  // ---- main recurrence ----
  for (int t = 0; t < NT; ++t) {
    const int cur = t & 1, nxt = cur ^ 1;
    const bool pf = (t + 1 < NT);

    // prefetch x(t+1) into regs; latency hides under the 96 MFMAs
    float4 v0, v1, v2, v3;
    if (pf) {
      const float4* src =
          (const float4*)(emb + (size_t)idxs[(t + 1) * ROWS + sr] * NH + sp * 16);
      v0 = src[0]; v1 = src[1]; v2 = src[2]; v3 = src[3];
    }

    const unsigned short* hsc = hs[cur];
    const unsigned short* xsc = xs[cur];
    unsigned short* hsn = hs[nxt];

    #pragma unroll
    for (int m = 0; m < 4; ++m) {
      // fused accumulators: aR/aI hold gi+gh (+both biases); aNI/aNH separate
      f32x4 aR = f32x4{biasRI[0], biasRI[0], biasRI[0], biasRI[0]};
      f32x4 aI = f32x4{biasRI[1], biasRI[1], biasRI[1], biasRI[1]};
      f32x4 aNI = f32x4{biasNI, biasNI, biasNI, biasNI};
      f32x4 aNH = f32x4{biasNH, biasNH, biasNH, biasNH};

      int arow = m * 16 + l15;
      int alin = arow * NH + l4 * 8;  // bits 3-4
      int sw2 = (arow & 7) << 3;      // bits 3-5
      __builtin_amdgcn_s_setprio(1);
      #pragma unroll
      for (int kk = 0; kk < 4; ++kk) {
        int e = (alin + kk * 32) ^ sw2;  // kk*32: bits 5-6, carry-free; XOR full index
        bf16x8 ah = __builtin_bit_cast(bf16x8, *(const short8*)&hsc[e]);
        bf16x8 ax = __builtin_bit_cast(bf16x8, *(const short8*)&xsc[e]);
        aR = __builtin_amdgcn_mfma_f32_16x16x32_bf16(ax, wih[0][kk], aR, 0, 0, 0);
        aR = __builtin_amdgcn_mfma_f32_16x16x32_bf16(ah, whh[0][kk], aR, 0, 0, 0);
        aI = __builtin_amdgcn_mfma_f32_16x16x32_bf16(ax, wih[1][kk], aI, 0, 0, 0);
        aI = __builtin_amdgcn_mfma_f32_16x16x32_bf16(ah, whh[1][kk], aI, 0, 0, 0);
        aNI = __builtin_amdgcn_mfma_f32_16x16x32_bf16(ax, wih[2][kk], aNI, 0, 0, 0);
        aNH = __builtin_amdgcn_mfma_f32_16x16x32_bf16(ah, whh[2][kk], aNH, 0, 0, 0);
      }
      __builtin_amdgcn_s_setprio(0);

      const f32x4 gq = *(const f32x4*)&gbuf[cur][m * 16 + l4 * 4];
      #pragma unroll
      for (int j = 0; j < 4; ++j) {
        int row = m * 16 + l4 * 4 + j;
        float rg = frcp(1.0f + exp2neg(aR[j]));           // sigm, pre-scaled arg
        float ig = frcp(1.0f + exp2neg(aI[j]));
        float an = fmaf(rg, aNH[j], aNI[j]);              // 2*log2e*(i_n + r*h_n)
        float ng = fmaf(2.0f, frcp(1.0f + exp2neg(an)), -1.0f);  // tanh
        float c = gq[j] * ig;                             // gates pre-thresholded
        float hy = fmaf(c, ng - hm[m][j], hm[m][j]);
        hm[m][j] = hy;
        hsn[(row * NH + col) ^ ((row & 7) << 3)] = bfbits(hy);
      }
    }

    if (pf) {
      short8 s0, s1;
      s0[0] = bfbits(v0.x); s0[1] = bfbits(v0.y); s0[2] = bfbits(v0.z); s0[3] = bfbits(v0.w);
      s0[4] = bfbits(v1.x); s0[5] = bfbits(v1.y); s0[6] = bfbits(v1.z); s0[7] = bfbits(v1.w);
      s1[0] = bfbits(v2.x); s1[1] = bfbits(v2.y); s1[2] = bfbits(v2.z); s1[3] = bfbits(v2.w);
      s1[4] = bfbits(v3.x); s1[5] = bfbits(v3.y); s1[6] = bfbits(v3.z); s1[7] = bfbits(v3.w);
      int base = sr * NH + sp * 16;
      int sw = (sr & 7) << 3;
      *(short8*)&xs[nxt][base ^ sw] = s0;
      *(short8*)&xs[nxt][(base + 8) ^ sw] = s1;
      gate_from(nxt, v0, v1, v2, v3);  // g(t+1) in the staging shadow
    }
    __syncthreads();
  }

  // ---- epilogue: out[b][I][h] ----
  #pragma unroll
  for (int m = 0; m < 4; ++m) {
    #pragma unroll
    for (int j = 0; j < 4; ++j) {
      int row = m * 16 + l4 * 4 + j;
      out[(size_t)(R0 + row) * (NINT * NH) + I * NH + col] = hm[m][j];
    }
  }
}

extern "C" void kernel_launch(void* const* d_in, const int* in_sizes, int n_in,
                              void* d_out, int out_size, void* d_ws, size_t ws_size,
                              hipStream_t stream) {
  const int* inputs = (const int*)d_in[0];
  const float* emb = (const float*)d_in[1];
  const float* w_int = (const float*)d_in[2];
  const float* w_ih = (const float*)d_in[3];
  const float* w_hh = (const float*)d_in[4];
  const float* b_ih = (const float*)d_in[5];
  const float* b_hh = (const float*)d_in[6];
  const float* h0 = (const float*)d_in[7];
  float* out = (float*)d_out;

  dim3 grid(NINT * (NB / ROWS));  // 256 blocks, one per CU
  dim3 block(512);
  gru_fused<<<grid, block, 0, stream>>>(inputs, emb, w_int, w_ih, w_hh, b_ih,
                                        b_hh, h0, out);
}